// Round 12
// baseline (4445.559 us; speedup 1.0000x reference)
//
#include <hip/hip_runtime.h>

typedef unsigned short u16;
typedef unsigned int u32;
typedef unsigned long long u64;
typedef __bf16 bfrag __attribute__((ext_vector_type(8)));
typedef float v4f __attribute__((ext_vector_type(4)));

#define DI __device__ __forceinline__

DI float bf2f(u16 b){ union{u32 u; float f;} c; c.u = ((u32)b)<<16; return c.f; }
DI u16 f2bf(float f){ union{float f; u32 u;} c; c.f=f; u32 u=c.u; return (u16)((u + 0x7FFFu + ((u>>16)&1u))>>16); }
DI float sigm(float x){ return 1.0f/(1.0f+__expf(-x)); }
DI float tanhf_(float x){ float a=fabsf(x); float e=__expf(2.0f*a); float r=1.0f-2.0f/(e+1.0f); return x<0.0f? -r : r; }

// ---------------- merged fp32 -> (hi,lo) bf16 split for all 4 weight matrices + eflags zero.
DI void cvt_one(const float* __restrict__ src, u16* __restrict__ hi, u16* __restrict__ lo, u32 i){
  float v = src[i]; u16 h = f2bf(v); hi[i] = h; lo[i] = f2bf(v - bf2f(h));
}
__global__ __launch_bounds__(256) void k_cvt4(const float* __restrict__ s0, u16* __restrict__ h0p, u16* __restrict__ l0p,
                                              const float* __restrict__ s1, u16* __restrict__ h1p, u16* __restrict__ l1p,
                                              const float* __restrict__ s2, u16* __restrict__ h2p, u16* __restrict__ l2p,
                                              const float* __restrict__ s3, u16* __restrict__ h3p, u16* __restrict__ l3p,
                                              u32* __restrict__ ef){
  u32 b = blockIdx.x, tid = threadIdx.x;
  if (b < 784u)            cvt_one(s0, h0p, l0p, b*256u + tid);                 // 200704
  else if (b < 1568u)      cvt_one(s1, h1p, l1p, (b-784u)*256u + tid);          // 200704
  else if (b < 2464u)      cvt_one(s2, h2p, l2p, (b-1568u)*256u + tid);         // 229376
  else if (b < 3488u)      cvt_one(s3, h3p, l3p, (b-2464u)*256u + tid);         // 262144
  else {                                                                        // eflags
    #pragma unroll
    for (int j=0;j<4;j++) ef[(u32)j*256u + tid] = 0u;
  }
}

// ---------------- fused conv stack: one block per image, full chain x -> y5.
// conv1+conv2 strip-pipelined (12 strips of 8 y2-rows; y1 strip = 18 rows, 8.1 KB LDS),
// then conv3 (y2 LDS -> y3 LDS), then conv4 (y3 LDS -> y5 global).
// Per-output accumulation order identical to the separate k_conv1..4 kernels.
// LDS: wsh 30.4K + y2s 86K + y1s 8.1K + y3s 14.3K = 138.8 KB -> 1 block/CU.
__global__ __launch_bounds__(256, 1) void k_convf(const float* __restrict__ x,
    const float* __restrict__ c1w, const float* __restrict__ c1b,
    const float* __restrict__ c2w, const float* __restrict__ c2b,
    const float* __restrict__ c3w, const float* __restrict__ c3b,
    const float* __restrict__ c4w, const float* __restrict__ c4b,
    float* __restrict__ y5){
  __shared__ __align__(16) float wsh[7592]; // w2[0,576) w3[576,2880) w4[2880,7488) b1@7488 b2@7492 b3@7508 b4@7524 w1@7556
  __shared__ __align__(16) float y2s[21504];
  __shared__ __align__(16) float y1s[2016];
  __shared__ __align__(16) float y3s[3584];
  u32 tid = threadIdx.x, b = blockIdx.x;
  const float* xb = x + (u64)b*10752u;
  for (u32 it=tid; it<576u;  it+=256u) wsh[it]        = c2w[it];
  for (u32 it=tid; it<2304u; it+=256u) wsh[576u+it]   = c3w[it];
  for (u32 it=tid; it<4608u; it+=256u) wsh[2880u+it]  = c4w[it];
  if (tid < 36u) wsh[7556u+tid] = c1w[tid];
  if (tid < 4u)  wsh[7488u+tid] = c1b[tid];
  if (tid < 16u) wsh[7492u+tid] = c2b[tid];
  if (tid < 16u) wsh[7508u+tid] = c3b[tid];
  if (tid < 32u) wsh[7524u+tid] = c4b[tid];
  __syncthreads();
  // ---- conv1+conv2, 12 strips of 8 pooled y2-rows
  for (u32 s=0; s<12u; s++){
    // phase 1: y1 strip rows gr = 16s-1+j (j=0..17), 4 ch x 18 x 28; out-of-range rows = 0 (pad)
    for (u32 it=tid; it<2016u; it+=256u){
      u32 ch = it/504u, rem = it - ch*504u;
      u32 j = rem/28u, c = rem - j*28u;
      int gr = 16*(int)s - 1 + (int)j;
      float m = 0.0f;
      if ((u32)gr < 192u){
        float bc = wsh[7488u+ch];
        #pragma unroll
        for (int py=0; py<2; py++){
          float a = bc;
          #pragma unroll
          for (int dy=0; dy<3; dy++){
            int iy = 2*gr + py - 1 + dy;
            bool vy = (u32)iy < 384u;
            #pragma unroll
            for (int dx=0; dx<3; dx++){
              int ix = (int)c - 1 + dx;
              a += (vy && (u32)ix < 28u) ? xb[iy*28+ix]*wsh[7556u+ch*9u+(u32)(dy*3+dx)] : 0.0f;
            }
          }
          m = fmaxf(m, a);
        }
      }
      y1s[it] = m;
    }
    __syncthreads();
    // phase 2: y2 rows oy = 8s+r (r=0..7), 16 co x 8 x 14
    for (u32 it=tid; it<1792u; it+=256u){
      u32 co = it/112u, rem = it - co*112u;
      u32 r = rem/14u, ox = rem - r*14u;
      float a0=0.f, a1=0.f, a2=0.f, a3=0.f;
      #pragma unroll
      for (int ci=0; ci<4; ci++){
        const float* wp = &wsh[(co*4u+(u32)ci)*9u];
        #pragma unroll
        for (int py=0; py<2; py++)
          #pragma unroll
          for (int px=0; px<2; px++){
            float sacc = (py==0) ? (px==0 ? a0 : a1) : (px==0 ? a2 : a3);
            #pragma unroll
            for (int dy=0; dy<3; dy++){
              u32 lr = 2u*r + (u32)(py+dy);
              #pragma unroll
              for (int dx=0; dx<3; dx++){
                int lc = 2*(int)ox + px - 1 + dx;
                sacc += ((u32)lc < 28u) ? y1s[(u32)ci*504u + lr*28u + (u32)lc]*wp[dy*3+dx] : 0.0f;
              }
            }
            if (py==0){ if (px==0) a0=sacc; else a1=sacc; } else { if (px==0) a2=sacc; else a3=sacc; }
          }
      }
      float m = fmaxf(fmaxf(a0,a1), fmaxf(a2,a3)) + wsh[7492u+co];
      y2s[co*1344u + (8u*s+r)*14u + ox] = fmaxf(m, 0.0f);
    }
    __syncthreads();   // phase-2 reads done before next strip overwrites y1s; last strip: y2s ready
  }
  // ---- conv3: y2s -> y3s, items (co,oy) = 16x32 = 512, 7 ox each
  for (u32 it=tid; it<512u; it+=256u){
    u32 co = it>>5, oy = it&31u;
    float acc[7][6];
    #pragma unroll
    for (int i=0;i<7;i++){
      #pragma unroll
      for (int j=0;j<6;j++) acc[i][j]=0.0f;
    }
    for (int ci=0; ci<16; ci++){
      float win[5][16];
      #pragma unroll
      for (int rr=0; rr<5; rr++){
        int iy = 3*(int)oy - 1 + rr;
        bool vy = (u32)iy < 96u;
        #pragma unroll
        for (int cc=0; cc<16; cc++){
          int ix = cc-1;
          win[rr][cc] = (vy && (u32)ix<14u) ? y2s[(u32)ci*1344u + (u32)iy*14u + (u32)ix] : 0.0f;
        }
      }
      float wf[9];
      #pragma unroll
      for (int j=0;j<9;j++) wf[j] = wsh[576u + (co*16u+(u32)ci)*9u + (u32)j];
      #pragma unroll
      for (int ox=0; ox<7; ox++){
        #pragma unroll
        for (int py=0; py<3; py++)
          #pragma unroll
          for (int px=0; px<2; px++){
            float sacc = acc[ox][py*2+px];
            #pragma unroll
            for (int dy=0; dy<3; dy++)
              #pragma unroll
              for (int dx=0; dx<3; dx++)
                sacc += win[py+dy][2*ox+px+dx]*wf[dy*3+dx];
            acc[ox][py*2+px] = sacc;
          }
      }
    }
    float bc = wsh[7508u+co];
    #pragma unroll
    for (int ox=0; ox<7; ox++){
      float m = acc[ox][0];
      #pragma unroll
      for (int j=1;j<6;j++) m = fmaxf(m, acc[ox][j]);
      y3s[co*224u + oy*7u + (u32)ox] = fmaxf(m + bc, 0.0f);
    }
  }
  __syncthreads();
  // ---- conv4: y3s -> y5, items (oy,cp) = 32x16 = 512, 2 co x 7 ox each
  for (u32 it=tid; it<512u; it+=256u){
    u32 oy = it>>4, cp = it&15u;
    u32 co0 = cp*2u;
    float acc[2][7];
    #pragma unroll
    for (int i=0;i<2;i++){
      #pragma unroll
      for (int j=0;j<7;j++) acc[i][j]=0.0f;
    }
    for (int ci=0; ci<16; ci++){
      float win[3][9];
      #pragma unroll
      for (int rr=0; rr<3; rr++){
        int iy = (int)oy - 1 + rr;
        bool vy = (u32)iy < 32u;
        #pragma unroll
        for (int cc=0; cc<9; cc++){
          int ix = cc-1;
          win[rr][cc] = (vy && (u32)ix<7u) ? y3s[(u32)ci*224u + (u32)iy*7u + (u32)ix] : 0.0f;
        }
      }
      #pragma unroll
      for (int c2=0; c2<2; c2++){
        float wf[9];
        #pragma unroll
        for (int j=0;j<9;j++) wf[j] = wsh[2880u + ((co0+(u32)c2)*16u+(u32)ci)*9u + (u32)j];
        #pragma unroll
        for (int ox=0; ox<7; ox++){
          float sacc = acc[c2][ox];
          #pragma unroll
          for (int dy=0; dy<3; dy++)
            #pragma unroll
            for (int dx=0; dx<3; dx++)
              sacc += win[dy][ox+dx]*wf[dy*3+dx];
          acc[c2][ox] = sacc;
        }
      }
    }
    #pragma unroll
    for (int c2=0; c2<2; c2++){
      float bc = wsh[7524u+co0+(u32)c2];
      #pragma unroll
      for (int ox=0; ox<7; ox++)
        y5[((u64)b*32u + oy)*224u + (u32)ox*32u + (co0+(u32)c2)] = fmaxf(acc[c2][ox] + bc, 0.0f);
    }
  }
}

// ---------------- flag zeroing (1024 u32) — dec flags only (after enc7; aliases y5 region)
__global__ __launch_bounds__(1024) void k_zero(u32* __restrict__ p){
  p[threadIdx.x] = 0u;
}

// ---------------- encoder LSTM, 7-way split: 448 WGs (64 groups x 7 septiles), flag sync.
__global__ __launch_bounds__(512, 4) void k_enc7(const u16* __restrict__ WihHi, const u16* __restrict__ WihLo,
                                                 const u16* __restrict__ WhhHi, const u16* __restrict__ WhhLo,
                                                 const float* __restrict__ bih, const float* __restrict__ bhh,
                                                 const float* __restrict__ y5, const float* __restrict__ h0,
                                                 const float* __restrict__ c0, float* __restrict__ y8,
                                                 u32* __restrict__ eflags){
  __shared__ __align__(16) u16 Ahi[16*456], Alo[16*456];   // A-tile: k<224 x_t | 224..448 h_{t-1}
  __shared__ __align__(16) float gsh[16*132];
  __shared__ __align__(16) float bsh[128];
  u32 tid = threadIdx.x, w = tid>>6, lane = tid&63u, nl = lane&15u, quad = lane>>4;
  u32 bid = blockIdx.x, g = bid & 63u, q = bid >> 6;
  u32 b0 = g*16u, hc0 = q*32u;
  if (tid < 128u){
    u32 gi = tid>>5, col = gi*224u + hc0 + (tid&31u);
    bsh[tid] = bih[col] + bhh[col];
  }
  for (u32 it=tid; it<3584u; it+=512u){
    u32 r = it/224u, c = it - r*224u;
    float v = h0[c]; u16 hb = f2bf(v);
    Ahi[r*456u+224u+c] = hb; Alo[r*456u+224u+c] = f2bf(v - bf2f(hb));
  }
  float creg = c0[hc0 + (tid&31u)];   // cell (row=tid>>5, hl=tid&31)
  u32* fE = eflags + g*16u;
  const u32 col = (w>>1)*224u + hc0 + (w&1u)*16u + nl;   // global gate col for this wave's N-tile
  const u32 gl  = (w>>1)*32u  + (w&1u)*16u + nl;          // local gate col [0,128)
  __syncthreads();
  for (u32 t=0; t<32u; t++){
    // stage x_t
    #pragma unroll
    for (int i=0;i<7;i++){
      u32 item = (u32)i*512u + tid;
      u32 r = item/224u, c = item - r*224u;
      float v = y5[((u64)(b0+r)*32u + t)*224u + c];
      u16 hb = f2bf(v);
      Ahi[r*456u+c] = hb; Alo[r*456u+c] = f2bf(v - bf2f(hb));
    }
    __syncthreads();
    // gates for our N-tile: [x|h] @ [Wih|Whh]^T, 3-term split
    v4f acc = {};
    #pragma unroll
    for (int kt=0; kt<14; kt++){
      u32 ka = (u32)kt*32u + quad*8u;
      bfrag ah = *(const bfrag*)&Ahi[nl*456u + ka];
      bfrag al = *(const bfrag*)&Alo[nl*456u + ka];
      bfrag bh, bl;
      if (kt<7){
        u64 o = (u64)col*224u + ka;
        bh = *(const bfrag*)&WihHi[o]; bl = *(const bfrag*)&WihLo[o];
      } else {
        u64 o = (u64)col*224u + (ka - 224u);
        bh = *(const bfrag*)&WhhHi[o]; bl = *(const bfrag*)&WhhLo[o];
      }
      acc = __builtin_amdgcn_mfma_f32_16x16x32_bf16(ah, bh, acc, 0,0,0);
      acc = __builtin_amdgcn_mfma_f32_16x16x32_bf16(al, bh, acc, 0,0,0);
      acc = __builtin_amdgcn_mfma_f32_16x16x32_bf16(ah, bl, acc, 0,0,0);
    }
    #pragma unroll
    for (int rg=0; rg<4; rg++)
      gsh[(quad*4u+(u32)rg)*132u + gl] = acc[rg];
    __syncthreads();
    // cell for our 32 h-cols (1 cell/thread); write-through h to y8
    {
      u32 row = tid>>5, hl = tid&31u;
      float gi_ = gsh[row*132u +       hl] + bsh[hl];
      float gf_ = gsh[row*132u + 32u + hl] + bsh[32u+hl];
      float gg_ = gsh[row*132u + 64u + hl] + bsh[64u+hl];
      float go_ = gsh[row*132u + 96u + hl] + bsh[96u+hl];
      float cv = sigm(gf_)*creg + sigm(gi_)*tanhf_(gg_);
      float hv = sigm(go_)*tanhf_(cv);
      creg = cv;
      union{float f; u32 u;} cu; cu.f = hv;
      __hip_atomic_store((u32*)&y8[((u64)(b0+row)*32u + t)*224u + hc0 + hl], cu.u,
                         __ATOMIC_RELAXED, __HIP_MEMORY_SCOPE_AGENT);
    }
    __syncthreads();  // drains vmcnt -> stores visible
    if (tid==0u)
      __hip_atomic_fetch_add(fE, 1u, __ATOMIC_RELEASE, __HIP_MEMORY_SCOPE_AGENT);
    if (t < 31u){
      if (tid==0u){
        while (__hip_atomic_load(fE, __ATOMIC_RELAXED, __HIP_MEMORY_SCOPE_AGENT) < 7u*(t+1u))
          __builtin_amdgcn_s_sleep(2);
      }
      __syncthreads();
      // reload full h_t (all 224 cols) from y8, re-split hi/lo
      for (u32 it=tid; it<3584u; it+=512u){
        u32 r = it/224u, c = it - r*224u;
        u32 uv = __hip_atomic_load((const u32*)&y8[((u64)(b0+r)*32u + t)*224u + c],
                                   __ATOMIC_RELAXED, __HIP_MEMORY_SCOPE_AGENT);
        union{u32 u; float f;} cu; cu.u = uv;
        u16 hb = f2bf(cu.f);
        Ahi[r*456u+224u+c] = hb; Alo[r*456u+224u+c] = f2bf(cu.f - bf2f(hb));
      }
      // next iteration's x-stage + barrier orders these writes before MFMA reads
    }
  }
}

// ---------------- decoder, 4-way split: 256 WGs (64 groups x 4 quarters), group-local flag sync.
// (round-3 configuration, measured 888 us — the best of 5 dec variants tried)
__global__ __launch_bounds__(512) void k_dec4(const float* __restrict__ y8,
    const float* __restrict__ attw, const float* __restrict__ attb,
    const u16* __restrict__ WihHi, const u16* __restrict__ WihLo,
    const u16* __restrict__ WhhHi, const u16* __restrict__ WhhLo,
    const float* __restrict__ bih, const float* __restrict__ bhh,
    u32* __restrict__ hist, u32* __restrict__ ctxc, u32* __restrict__ flags){
  __shared__ __align__(16) u16 Ahi[16*488], Alo[16*488];   // A-tile: k<224 ctx | 224..480 h
  __shared__ __align__(16) float hfull[16*256];
  __shared__ __align__(16) float gsh[16*260];
  __shared__ __align__(16) float esc[16*33];
  __shared__ __align__(16) float alp[16*33];
  __shared__ __align__(16) float bsh[256];
  u32 tid=threadIdx.x, w=tid>>6, lane=tid&63u, nl=lane&15u, quad=lane>>4;
  u32 p = blockIdx.x, xcd = p&7u, slot = p>>3;
  u32 q = xcd>>1;                     // same weight quarter per XCD (L2 locality)
  u32 g = (xcd&1u)*32u + slot;        // group 0..63
  u32 b0 = g*16u, hc0 = q*64u;
  for (u32 it=tid; it<256u; it+=512u){
    u32 gi = it>>6, col = gi*256u + hc0 + (it&63u);
    bsh[it] = bih[col] + bhh[col];
  }
  for (u32 it=tid; it<4096u; it+=512u){
    u32 r=it>>8, c=it&255u;
    Ahi[r*488u+224u+c]=0; Alo[r*488u+224u+c]=0;
    hfull[it]=0.0f;
  }
  {
    u32 r=tid>>5, t=tid&31u;
    const float* yr = y8 + ((u64)(b0+r)*32u + t)*224u;
    const float* we = attw + 256;
    float sacc=0.0f;
    #pragma unroll 8
    for (int j=0;j<224;j++) sacc += yr[j]*we[j];
    esc[r*33u+t] = sacc + attb[0];
  }
  float cst[2] = {0.0f, 0.0f};
  u32* fh = flags + g*16u;
  u32* fc = flags + g*16u + 8u;
  const u32 nt0 = w, nt1 = w + 8u;
  const u32 col0 = (nt0>>2)*256u + hc0 + (nt0&3u)*16u + nl;
  const u32 col1 = (nt1>>2)*256u + hc0 + (nt1&3u)*16u + nl;
  const u32 gl0  = (nt0>>2)*64u + (nt0&3u)*16u + nl;
  const u32 gl1  = (nt1>>2)*64u + (nt1&3u)*16u + nl;
  __syncthreads();
  for (u32 s=0; s<25u; s++){
    // ---- phase A: wait siblings' h[s-1], load packed h -> hfull + A-tile
    if (s>0u){
      if (tid==0u){
        while (__hip_atomic_load(fh, __ATOMIC_RELAXED, __HIP_MEMORY_SCOPE_AGENT) < 4u*s)
          __builtin_amdgcn_s_sleep(2);
      }
      __syncthreads();
      u32* hrow = hist + ((u64)(s-1u)*1024u + b0)*256u;
      for (u32 it=tid; it<4096u; it+=512u){
        u32 v = __hip_atomic_load(&hrow[it], __ATOMIC_RELAXED, __HIP_MEMORY_SCOPE_AGENT);
        u32 r = it>>8, c = it&255u;
        u16 hb = (u16)(v>>16), lb = (u16)(v&0xFFFFu);
        Ahi[r*488u+224u+c] = hb; Alo[r*488u+224u+c] = lb;
        hfull[it] = bf2f(hb) + bf2f(lb);
      }
      __syncthreads();
    }
    // ---- scores + softmax (redundant across the 4 siblings; cheap)
    {
      u32 r=tid>>5, t=tid&31u;
      float part=0.0f;
      if (s>0u){
        #pragma unroll
        for (int qq=0; qq<8; qq++){
          u32 c = t + (u32)qq*32u;
          part += hfull[r*256u+c]*attw[c];
        }
        #pragma unroll
        for (int off=16; off; off>>=1) part += __shfl_xor(part, off, 32);
      }
      float sv = esc[r*33u+t] + part;
      float mx = sv;
      #pragma unroll
      for (int off=16; off; off>>=1) mx = fmaxf(mx, __shfl_xor(mx, off, 32));
      float e = __expf(sv-mx);
      float ssum = e;
      #pragma unroll
      for (int off=16; off; off>>=1) ssum += __shfl_xor(ssum, off, 32);
      alp[r*33u+t] = e/ssum;
    }
    __syncthreads();
    // ---- phase B: ctx quarter (56 cols), pack hi|lo, write-through store
    u32* cdst = ctxc + (u64)(s&1u)*229376u + (u64)g*3584u;
    for (u32 it=tid; it<896u; it+=512u){
      u32 rr = it/56u, cc = it - rr*56u + q*56u;
      const float* yb = y8 + (u64)(b0+rr)*32u*224u + cc;
      float a0=0.0f;
      #pragma unroll
      for (int tt=0; tt<32; tt++) a0 += alp[rr*33u+(u32)tt]*yb[(u32)tt*224u];
      u16 hb = f2bf(a0), lb = f2bf(a0 - bf2f(hb));
      __hip_atomic_store(&cdst[rr*224u+cc], ((u32)hb<<16)|(u32)lb, __ATOMIC_RELAXED, __HIP_MEMORY_SCOPE_AGENT);
    }
    __syncthreads();  // drains vmcnt -> stores globally visible
    if (tid==0u){
      __hip_atomic_fetch_add(fc, 1u, __ATOMIC_RELEASE, __HIP_MEMORY_SCOPE_AGENT);
      while (__hip_atomic_load(fc, __ATOMIC_RELAXED, __HIP_MEMORY_SCOPE_AGENT) < 4u*(s+1u))
        __builtin_amdgcn_s_sleep(2);
    }
    __syncthreads();
    // ---- phase C: full ctx -> A-tile (L1-bypass loads; parity buffer)
    for (u32 it=tid; it<3584u; it+=512u){
      u32 v = __hip_atomic_load(&cdst[it], __ATOMIC_RELAXED, __HIP_MEMORY_SCOPE_AGENT);
      u32 rr = it/224u, cc = it - rr*224u;
      Ahi[rr*488u+cc] = (u16)(v>>16); Alo[rr*488u+cc] = (u16)(v&0xFFFFu);
    }
    __syncthreads();
    // ---- phase D: gates = [ctx|h] @ [Wih|Whh]^T for our 256 gate cols, 3-term split
    v4f acc0 = {}, acc1 = {};
    #pragma unroll
    for (int kt=0; kt<15; kt++){
      u32 ka = (u32)kt*32u + quad*8u;
      bfrag afh = *(const bfrag*)&Ahi[nl*488u + ka];
      bfrag afl = *(const bfrag*)&Alo[nl*488u + ka];
      bfrag b0h, b0l, b1h, b1l;
      if (kt<7){
        u64 o0 = (u64)col0*224u + ka, o1 = (u64)col1*224u + ka;
        b0h = *(const bfrag*)&WihHi[o0]; b0l = *(const bfrag*)&WihLo[o0];
        b1h = *(const bfrag*)&WihHi[o1]; b1l = *(const bfrag*)&WihLo[o1];
      } else {
        u32 kb = ka - 224u;
        u64 o0 = (u64)col0*256u + kb, o1 = (u64)col1*256u + kb;
        b0h = *(const bfrag*)&WhhHi[o0]; b0l = *(const bfrag*)&WhhLo[o0];
        b1h = *(const bfrag*)&WhhHi[o1]; b1l = *(const bfrag*)&WhhLo[o1];
      }
      acc0 = __builtin_amdgcn_mfma_f32_16x16x32_bf16(afh, b0h, acc0, 0,0,0);
      acc0 = __builtin_amdgcn_mfma_f32_16x16x32_bf16(afl, b0h, acc0, 0,0,0);
      acc0 = __builtin_amdgcn_mfma_f32_16x16x32_bf16(afh, b0l, acc0, 0,0,0);
      acc1 = __builtin_amdgcn_mfma_f32_16x16x32_bf16(afh, b1h, acc1, 0,0,0);
      acc1 = __builtin_amdgcn_mfma_f32_16x16x32_bf16(afl, b1h, acc1, 0,0,0);
      acc1 = __builtin_amdgcn_mfma_f32_16x16x32_bf16(afh, b1l, acc1, 0,0,0);
    }
    #pragma unroll
    for (int rg=0; rg<4; rg++){
      gsh[(quad*4u+(u32)rg)*260u + gl0] = acc0[rg];
      gsh[(quad*4u+(u32)rg)*260u + gl1] = acc1[rg];
    }
    __syncthreads();
    // ---- phase E: cell for our 64 h-cols; post packed h to hist[s]
    u32* hdst = hist + ((u64)s*1024u + b0)*256u + hc0;
    #pragma unroll
    for (int k2=0; k2<2; k2++){
      u32 l = (u32)k2*512u + tid;
      u32 row = l>>6, hl = l&63u;
      float gi_ = gsh[row*260u + hl]         + bsh[hl];
      float gf_ = gsh[row*260u + 64u  + hl]  + bsh[64u+hl];
      float gg_ = gsh[row*260u + 128u + hl]  + bsh[128u+hl];
      float go_ = gsh[row*260u + 192u + hl]  + bsh[192u+hl];
      float cv = sigm(gf_)*cst[k2] + sigm(gi_)*tanhf_(gg_);
      float hv = sigm(go_)*tanhf_(cv);
      cst[k2] = cv;
      u16 hb = f2bf(hv), lb = f2bf(hv - bf2f(hb));
      __hip_atomic_store(&hdst[row*256u + hl], ((u32)hb<<16)|(u32)lb, __ATOMIC_RELAXED, __HIP_MEMORY_SCOPE_AGENT);
    }
    __syncthreads();  // drains vmcnt
    if (tid==0u)
      __hip_atomic_fetch_add(fh, 1u, __ATOMIC_RELEASE, __HIP_MEMORY_SCOPE_AGENT);
  }
}

// ---------------- out projection from packed h history: (B, VOCAB, OUT_LEN) fp32
__global__ __launch_bounds__(256) void k_out(const u32* __restrict__ hist, const float* __restrict__ outw,
                                             const float* __restrict__ outb, float* __restrict__ outp){
  __shared__ __align__(16) float wsh[29*260];
  __shared__ __align__(16) float hrow[256];
  u32 tid = threadIdx.x, b = blockIdx.x;
  for (u32 it=tid; it<7424u; it+=256u){
    u32 v = it/256u, c = it&255u;
    wsh[v*260u+c] = outw[v*256u+c];
  }
  __syncthreads();
  for (u32 s=0; s<25u; s++){
    u32 v = hist[((u64)s*1024u + b)*256u + tid];
    hrow[tid] = bf2f((u16)(v>>16)) + bf2f((u16)(v&0xFFFFu));
    __syncthreads();
    if (tid < 232u){
      u32 vv = tid>>3, k8 = tid&7u;
      float a = 0.0f;
      #pragma unroll
      for (int j=0;j<32;j++) a += hrow[k8*32u+(u32)j]*wsh[vv*260u + k8*32u + (u32)j];
      #pragma unroll
      for (int off=4; off; off>>=1) a += __shfl_xor(a, off, 8);
      if (k8==0u) outp[((u64)b*29u + vv)*25u + s] = a + outb[vv];
    }
    __syncthreads();
  }
}

extern "C" void kernel_launch(void* const* d_in, const int* in_sizes, int n_in,
                              void* d_out, int out_size, void* d_ws, size_t ws_size,
                              hipStream_t stream){
  (void)in_sizes; (void)n_in; (void)out_size; (void)ws_size;
  const float* x    = (const float*)d_in[0];
  const float* c1w  = (const float*)d_in[1];
  const float* c1b  = (const float*)d_in[2];
  const float* c2w  = (const float*)d_in[3];
  const float* c2b  = (const float*)d_in[4];
  const float* c3w  = (const float*)d_in[5];
  const float* c3b  = (const float*)d_in[6];
  const float* c4w  = (const float*)d_in[7];
  const float* c4b  = (const float*)d_in[8];
  const float* h0   = (const float*)d_in[9];
  const float* c0   = (const float*)d_in[10];
  const float* lWih = (const float*)d_in[11];
  const float* lWhh = (const float*)d_in[12];
  const float* lbih = (const float*)d_in[13];
  const float* lbhh = (const float*)d_in[14];
  const float* attw = (const float*)d_in[15];
  const float* attb = (const float*)d_in[16];
  const float* dWih = (const float*)d_in[17];
  const float* dWhh = (const float*)d_in[18];
  const float* dbih = (const float*)d_in[19];
  const float* dbhh = (const float*)d_in[20];
  const float* outw = (const float*)d_in[21];
  const float* outb = (const float*)d_in[22];
  float* out = (float*)d_out;   // reference output dtype is float32
  char* ws = (char*)d_ws;
  // workspace (peak 62,291,968 B), with overlaps:
  //   y5  [0,29.36M)   (written by k_convf; conv intermediates all live in LDS now)
  //   y8  [29.36,58.72M) (written by k_enc7)
  //   dec phase (y5 dead): hist [0,26.21M) ctxc [26.21,28.05M) flags [28.05M,+4K)
  //   enc flags live in d_out (fully overwritten by k_out afterwards)
  float* y5  = (float*)(ws);
  float* y8  = (float*)(ws + 29360128ull);
  u32* hist  = (u32*)(ws);
  u32* ctxc  = (u32*)(ws + 26214400ull);
  u32* flags = (u32*)(ws + 28049408ull);
  u16* lWihHi = (u16*)(ws + 58720256ull);
  u16* lWihLo = (u16*)(ws + 59121664ull);
  u16* lWhhHi = (u16*)(ws + 59523072ull);
  u16* lWhhLo = (u16*)(ws + 59924480ull);
  u16* dWihHi = (u16*)(ws + 60325888ull);
  u16* dWihLo = (u16*)(ws + 60784640ull);
  u16* dWhhHi = (u16*)(ws + 61243392ull);
  u16* dWhhLo = (u16*)(ws + 61767680ull);
  u32* eflags = (u32*)d_out;

  k_cvt4<<<dim3(3489), dim3(256), 0, stream>>>(lWih, lWihHi, lWihLo,
                                               lWhh, lWhhHi, lWhhLo,
                                               dWih, dWihHi, dWihLo,
                                               dWhh, dWhhHi, dWhhLo, eflags);
  k_convf<<<dim3(1024), dim3(256), 0, stream>>>(x, c1w, c1b, c2w, c2b, c3w, c3b, c4w, c4b, y5);
  k_enc7 <<<dim3(448), dim3(512), 0, stream>>>(lWihHi, lWihLo, lWhhHi, lWhhLo, lbih, lbhh,
                                               y5, h0, c0, y8, eflags);
  k_zero <<<dim3(1), dim3(1024), 0, stream>>>(flags);
  k_dec4 <<<dim3(256), dim3(512), 0, stream>>>(y8, attw, attb, dWihHi, dWihLo, dWhhHi, dWhhLo,
                                               dbih, dbhh, hist, ctxc, flags);
  k_out  <<<dim3(1024), dim3(256), 0, stream>>>(hist, outw, outb, out);
}

// Round 13
// 2000.343 us; speedup vs baseline: 2.2224x; 2.2224x over previous
//
#include <hip/hip_runtime.h>

typedef unsigned short u16;
typedef unsigned int u32;
typedef unsigned long long u64;
typedef __bf16 bfrag __attribute__((ext_vector_type(8)));
typedef float v4f __attribute__((ext_vector_type(4)));

#define DI __device__ __forceinline__

DI float bf2f(u16 b){ union{u32 u; float f;} c; c.u = ((u32)b)<<16; return c.f; }
DI u16 f2bf(float f){ union{float f; u32 u;} c; c.f=f; u32 u=c.u; return (u16)((u + 0x7FFFu + ((u>>16)&1u))>>16); }
DI float sigm(float x){ return 1.0f/(1.0f+__expf(-x)); }
DI float tanhf_(float x){ float a=fabsf(x); float e=__expf(2.0f*a); float r=1.0f-2.0f/(e+1.0f); return x<0.0f? -r : r; }

// ---------------- merged fp32 -> (hi,lo) bf16 split for all 4 weight matrices + eflags zero.
DI void cvt_one(const float* __restrict__ src, u16* __restrict__ hi, u16* __restrict__ lo, u32 i){
  float v = src[i]; u16 h = f2bf(v); hi[i] = h; lo[i] = f2bf(v - bf2f(h));
}
__global__ __launch_bounds__(256) void k_cvt4(const float* __restrict__ s0, u16* __restrict__ h0p, u16* __restrict__ l0p,
                                              const float* __restrict__ s1, u16* __restrict__ h1p, u16* __restrict__ l1p,
                                              const float* __restrict__ s2, u16* __restrict__ h2p, u16* __restrict__ l2p,
                                              const float* __restrict__ s3, u16* __restrict__ h3p, u16* __restrict__ l3p,
                                              u32* __restrict__ ef){
  u32 b = blockIdx.x, tid = threadIdx.x;
  if (b < 784u)            cvt_one(s0, h0p, l0p, b*256u + tid);                 // 200704
  else if (b < 1568u)      cvt_one(s1, h1p, l1p, (b-784u)*256u + tid);          // 200704
  else if (b < 2464u)      cvt_one(s2, h2p, l2p, (b-1568u)*256u + tid);         // 229376
  else if (b < 3488u)      cvt_one(s3, h3p, l3p, (b-2464u)*256u + tid);         // 262144
  else {                                                                        // eflags
    #pragma unroll
    for (int j=0;j<4;j++) ef[(u32)j*256u + tid] = 0u;
  }
}

// ---------------- conv1 (batch quarter): x fp32 -> y1q fp32 (256,4,192,28)
__global__ __launch_bounds__(256) void k_conv1(const float* __restrict__ x, const float* __restrict__ w,
                                               const float* __restrict__ bias, float* __restrict__ y1q, u32 bbase){
  u32 gid = blockIdx.x*256u + threadIdx.x;
  u32 bl = gid/768u, r = gid - bl*768u;
  u32 oy = r>>2, xg = r&3u;
  const float* xb = x + (u64)(bbase+bl)*10752u;
  float win[4][9];
  #pragma unroll
  for (int rr=0; rr<4; rr++){
    int iy = 2*(int)oy - 1 + rr;
    bool vy = (u32)iy < 384u;
    #pragma unroll
    for (int cc=0; cc<9; cc++){
      int ix = (int)(xg*7u) + cc - 1;
      win[rr][cc] = (vy && (u32)ix < 28u) ? xb[iy*28 + ix] : 0.0f;
    }
  }
  #pragma unroll
  for (int co=0; co<4; co++){
    float wf[9];
    #pragma unroll
    for (int j=0;j<9;j++) wf[j] = w[co*9+j];
    float bc = bias[co];
    float* outp = y1q + ((u64)(bl*4u+co)*192u + oy)*28u + xg*7u;
    #pragma unroll
    for (int ox=0; ox<7; ox++){
      float m = 0.0f;
      #pragma unroll
      for (int py=0; py<2; py++){
        float s = bc;
        #pragma unroll
        for (int dy=0; dy<3; dy++)
          #pragma unroll
          for (int dx=0; dx<3; dx++)
            s += win[py+dy][ox+dx]*wf[dy*3+dx];
        m = fmaxf(m, s);
      }
      outp[ox] = m;
    }
  }
}

// ---------------- conv2 (quarter): y1q -> y2q fp32 (256,16,96,14)
__global__ __launch_bounds__(256) void k_conv2(const float* __restrict__ y1q, const float* __restrict__ w,
                                               const float* __restrict__ bias, float* __restrict__ y2q){
  u32 gid = blockIdx.x*256u + threadIdx.x;
  u32 bl = gid/1536u, r = gid - bl*1536u;
  u32 oy = r>>4, xg = (r>>3)&1u, cp = r&7u;
  const float* inb = y1q + (u64)bl*21504u;
  float acc[2][7][4];
  #pragma unroll
  for (int c2=0;c2<2;c2++)
    #pragma unroll
    for (int i=0;i<7;i++){ acc[c2][i][0]=0.f;acc[c2][i][1]=0.f;acc[c2][i][2]=0.f;acc[c2][i][3]=0.f; }
  for (int ci=0; ci<4; ci++){
    float win[4][16];
    const float* pl = inb + ci*5376;
    #pragma unroll
    for (int rr=0; rr<4; rr++){
      int iy = 2*(int)oy - 1 + rr;
      bool vy = (u32)iy < 192u;
      #pragma unroll
      for (int cc=0; cc<16; cc++){
        int ix = (int)(xg*14u) + cc - 1;
        win[rr][cc] = (vy && (u32)ix<28u) ? pl[iy*28+ix] : 0.0f;
      }
    }
    float wf[2][9];
    #pragma unroll
    for (int c2=0;c2<2;c2++)
      #pragma unroll
      for (int j=0;j<9;j++) wf[c2][j] = w[((cp*2u+(u32)c2)*4u+(u32)ci)*9u+j];
    #pragma unroll
    for (int c2=0;c2<2;c2++)
      #pragma unroll
      for (int ol=0; ol<7; ol++)
        #pragma unroll
        for (int py=0; py<2; py++)
          #pragma unroll
          for (int px=0; px<2; px++){
            float s = acc[c2][ol][py*2+px];
            #pragma unroll
            for (int dy=0; dy<3; dy++)
              #pragma unroll
              for (int dx=0; dx<3; dx++)
                s += win[py+dy][2*ol+px+dx]*wf[c2][dy*3+dx];
            acc[c2][ol][py*2+px] = s;
          }
  }
  #pragma unroll
  for (int c2=0;c2<2;c2++){
    u32 co = cp*2u+(u32)c2;
    float bc = bias[co];
    float* outp = y2q + ((u64)(bl*16u+co)*96u + oy)*14u + xg*7u;
    #pragma unroll
    for (int ol=0; ol<7; ol++){
      float m = fmaxf(fmaxf(acc[c2][ol][0],acc[c2][ol][1]), fmaxf(acc[c2][ol][2],acc[c2][ol][3])) + bc;
      outp[ol] = fmaxf(m, 0.0f);
    }
  }
}

// ---------------- conv3 (quarter): y2q -> y3 fp32 (1024,16,32,7)
__global__ __launch_bounds__(256) void k_conv3(const float* __restrict__ y2q, const float* __restrict__ w,
                                               const float* __restrict__ bias, float* __restrict__ y3, u32 bbase){
  u32 gid = blockIdx.x*256u + threadIdx.x;
  u32 bl = gid/512u, r = gid - bl*512u;
  u32 oy = r>>4, co = r&15u;
  const float* inb = y2q + (u64)bl*21504u;
  float acc[7][6];
  #pragma unroll
  for (int i=0;i<7;i++){
    #pragma unroll
    for (int j=0;j<6;j++) acc[i][j]=0.0f;
  }
  for (int ci=0; ci<16; ci++){
    float win[5][16];
    const float* pl = inb + ci*1344;
    #pragma unroll
    for (int rr=0; rr<5; rr++){
      int iy = 3*(int)oy - 1 + rr;
      bool vy = (u32)iy < 96u;
      #pragma unroll
      for (int cc=0; cc<16; cc++){
        int ix = cc-1;
        win[rr][cc] = (vy && (u32)ix<14u) ? pl[iy*14+ix] : 0.0f;
      }
    }
    float wf[9];
    #pragma unroll
    for (int j=0;j<9;j++) wf[j] = w[((u32)co*16u+(u32)ci)*9u+j];
    #pragma unroll
    for (int ox=0; ox<7; ox++){
      #pragma unroll
      for (int py=0; py<3; py++)
        #pragma unroll
        for (int px=0; px<2; px++){
          float s = acc[ox][py*2+px];
          #pragma unroll
          for (int dy=0; dy<3; dy++)
            #pragma unroll
            for (int dx=0; dx<3; dx++)
              s += win[py+dy][2*ox+px+dx]*wf[dy*3+dx];
          acc[ox][py*2+px] = s;
        }
    }
  }
  float bc = bias[co];
  float* outp = y3 + ((u64)((bbase+bl)*16u+co)*32u + oy)*7u;
  #pragma unroll
  for (int ox=0; ox<7; ox++){
    float m = acc[ox][0];
    #pragma unroll
    for (int j=1;j<6;j++) m = fmaxf(m, acc[ox][j]);
    outp[ox] = fmaxf(m + bc, 0.0f);
  }
}

// ---------------- conv4 (full): y3 -> y5 fp32 (1024,32,224)  [ad = ox*32+co]
__global__ __launch_bounds__(256) void k_conv4(const float* __restrict__ y3, const float* __restrict__ w,
                                               const float* __restrict__ bias, float* __restrict__ y5){
  u32 gid = blockIdx.x*256u + threadIdx.x;
  u32 b = gid/512u, r = gid - b*512u;
  u32 oy = r>>4, cp = r&15u;
  u32 co0 = cp*2u;
  const float* inb = y3 + (u64)b*3584u;
  float acc[2][7];
  #pragma unroll
  for (int i=0;i<2;i++){
    #pragma unroll
    for (int j=0;j<7;j++) acc[i][j]=0.0f;
  }
  for (int ci=0; ci<16; ci++){
    float win[3][9];
    const float* pl = inb + ci*224;
    #pragma unroll
    for (int rr=0; rr<3; rr++){
      int iy = (int)oy - 1 + rr;
      bool vy = (u32)iy < 32u;
      #pragma unroll
      for (int cc=0; cc<9; cc++){
        int ix = cc-1;
        win[rr][cc] = (vy && (u32)ix<7u) ? pl[iy*7+ix] : 0.0f;
      }
    }
    #pragma unroll
    for (int c2=0; c2<2; c2++){
      float wf[9];
      #pragma unroll
      for (int j=0;j<9;j++) wf[j] = w[((co0+(u32)c2)*16u+(u32)ci)*9u+j];
      #pragma unroll
      for (int ox=0; ox<7; ox++){
        float s = acc[c2][ox];
        #pragma unroll
        for (int dy=0; dy<3; dy++)
          #pragma unroll
          for (int dx=0; dx<3; dx++)
            s += win[dy][ox+dx]*wf[dy*3+dx];
        acc[c2][ox] = s;
      }
    }
  }
  #pragma unroll
  for (int c2=0; c2<2; c2++){
    float bc = bias[co0+(u32)c2];
    #pragma unroll
    for (int ox=0; ox<7; ox++)
      y5[((u64)b*32u + oy)*224u + (u32)ox*32u + (co0+(u32)c2)] = fmaxf(acc[c2][ox] + bc, 0.0f);
  }
}

// ---------------- flag zeroing (1024 u32) — dec flags only (after enc7; aliases y5 region)
__global__ __launch_bounds__(1024) void k_zero(u32* __restrict__ p){
  p[threadIdx.x] = 0u;
}

// ---------------- encoder LSTM, 7-way split: 448 WGs (64 groups x 7 septiles), flag sync.
__global__ __launch_bounds__(512, 4) void k_enc7(const u16* __restrict__ WihHi, const u16* __restrict__ WihLo,
                                                 const u16* __restrict__ WhhHi, const u16* __restrict__ WhhLo,
                                                 const float* __restrict__ bih, const float* __restrict__ bhh,
                                                 const float* __restrict__ y5, const float* __restrict__ h0,
                                                 const float* __restrict__ c0, float* __restrict__ y8,
                                                 u32* __restrict__ eflags){
  __shared__ __align__(16) u16 Ahi[16*456], Alo[16*456];   // A-tile: k<224 x_t | 224..448 h_{t-1}
  __shared__ __align__(16) float gsh[16*132];
  __shared__ __align__(16) float bsh[128];
  u32 tid = threadIdx.x, w = tid>>6, lane = tid&63u, nl = lane&15u, quad = lane>>4;
  u32 bid = blockIdx.x, g = bid & 63u, q = bid >> 6;
  u32 b0 = g*16u, hc0 = q*32u;
  if (tid < 128u){
    u32 gi = tid>>5, col = gi*224u + hc0 + (tid&31u);
    bsh[tid] = bih[col] + bhh[col];
  }
  for (u32 it=tid; it<3584u; it+=512u){
    u32 r = it/224u, c = it - r*224u;
    float v = h0[c]; u16 hb = f2bf(v);
    Ahi[r*456u+224u+c] = hb; Alo[r*456u+224u+c] = f2bf(v - bf2f(hb));
  }
  float creg = c0[hc0 + (tid&31u)];   // cell (row=tid>>5, hl=tid&31)
  u32* fE = eflags + g*16u;
  const u32 col = (w>>1)*224u + hc0 + (w&1u)*16u + nl;   // global gate col for this wave's N-tile
  const u32 gl  = (w>>1)*32u  + (w&1u)*16u + nl;          // local gate col [0,128)
  __syncthreads();
  for (u32 t=0; t<32u; t++){
    // stage x_t
    #pragma unroll
    for (int i=0;i<7;i++){
      u32 item = (u32)i*512u + tid;
      u32 r = item/224u, c = item - r*224u;
      float v = y5[((u64)(b0+r)*32u + t)*224u + c];
      u16 hb = f2bf(v);
      Ahi[r*456u+c] = hb; Alo[r*456u+c] = f2bf(v - bf2f(hb));
    }
    __syncthreads();
    // gates for our N-tile: [x|h] @ [Wih|Whh]^T, 3-term split
    v4f acc = {};
    #pragma unroll
    for (int kt=0; kt<14; kt++){
      u32 ka = (u32)kt*32u + quad*8u;
      bfrag ah = *(const bfrag*)&Ahi[nl*456u + ka];
      bfrag al = *(const bfrag*)&Alo[nl*456u + ka];
      bfrag bh, bl;
      if (kt<7){
        u64 o = (u64)col*224u + ka;
        bh = *(const bfrag*)&WihHi[o]; bl = *(const bfrag*)&WihLo[o];
      } else {
        u64 o = (u64)col*224u + (ka - 224u);
        bh = *(const bfrag*)&WhhHi[o]; bl = *(const bfrag*)&WhhLo[o];
      }
      acc = __builtin_amdgcn_mfma_f32_16x16x32_bf16(ah, bh, acc, 0,0,0);
      acc = __builtin_amdgcn_mfma_f32_16x16x32_bf16(al, bh, acc, 0,0,0);
      acc = __builtin_amdgcn_mfma_f32_16x16x32_bf16(ah, bl, acc, 0,0,0);
    }
    #pragma unroll
    for (int rg=0; rg<4; rg++)
      gsh[(quad*4u+(u32)rg)*132u + gl] = acc[rg];
    __syncthreads();
    // cell for our 32 h-cols (1 cell/thread); write-through h to y8
    {
      u32 row = tid>>5, hl = tid&31u;
      float gi_ = gsh[row*132u +       hl] + bsh[hl];
      float gf_ = gsh[row*132u + 32u + hl] + bsh[32u+hl];
      float gg_ = gsh[row*132u + 64u + hl] + bsh[64u+hl];
      float go_ = gsh[row*132u + 96u + hl] + bsh[96u+hl];
      float cv = sigm(gf_)*creg + sigm(gi_)*tanhf_(gg_);
      float hv = sigm(go_)*tanhf_(cv);
      creg = cv;
      union{float f; u32 u;} cu; cu.f = hv;
      __hip_atomic_store((u32*)&y8[((u64)(b0+row)*32u + t)*224u + hc0 + hl], cu.u,
                         __ATOMIC_RELAXED, __HIP_MEMORY_SCOPE_AGENT);
    }
    __syncthreads();  // drains vmcnt -> stores visible
    if (tid==0u)
      __hip_atomic_fetch_add(fE, 1u, __ATOMIC_RELEASE, __HIP_MEMORY_SCOPE_AGENT);
    if (t < 31u){
      if (tid==0u){
        while (__hip_atomic_load(fE, __ATOMIC_RELAXED, __HIP_MEMORY_SCOPE_AGENT) < 7u*(t+1u))
          __builtin_amdgcn_s_sleep(2);
      }
      __syncthreads();
      // reload full h_t (all 224 cols) from y8, re-split hi/lo
      for (u32 it=tid; it<3584u; it+=512u){
        u32 r = it/224u, c = it - r*224u;
        u32 uv = __hip_atomic_load((const u32*)&y8[((u64)(b0+r)*32u + t)*224u + c],
                                   __ATOMIC_RELAXED, __HIP_MEMORY_SCOPE_AGENT);
        union{u32 u; float f;} cu; cu.u = uv;
        u16 hb = f2bf(cu.f);
        Ahi[r*456u+224u+c] = hb; Alo[r*456u+224u+c] = f2bf(cu.f - bf2f(hb));
      }
      // next iteration's x-stage + barrier orders these writes before MFMA reads
    }
  }
}

// ---------------- decoder, 4-way split: 256 WGs (64 groups x 4 quarters), group-local flag sync.
// (round-3 configuration, measured 888 us — the best of 5 dec variants tried)
__global__ __launch_bounds__(512) void k_dec4(const float* __restrict__ y8,
    const float* __restrict__ attw, const float* __restrict__ attb,
    const u16* __restrict__ WihHi, const u16* __restrict__ WihLo,
    const u16* __restrict__ WhhHi, const u16* __restrict__ WhhLo,
    const float* __restrict__ bih, const float* __restrict__ bhh,
    u32* __restrict__ hist, u32* __restrict__ ctxc, u32* __restrict__ flags){
  __shared__ __align__(16) u16 Ahi[16*488], Alo[16*488];   // A-tile: k<224 ctx | 224..480 h
  __shared__ __align__(16) float hfull[16*256];
  __shared__ __align__(16) float gsh[16*260];
  __shared__ __align__(16) float esc[16*33];
  __shared__ __align__(16) float alp[16*33];
  __shared__ __align__(16) float bsh[256];
  u32 tid=threadIdx.x, w=tid>>6, lane=tid&63u, nl=lane&15u, quad=lane>>4;
  u32 p = blockIdx.x, xcd = p&7u, slot = p>>3;
  u32 q = xcd>>1;                     // same weight quarter per XCD (L2 locality)
  u32 g = (xcd&1u)*32u + slot;        // group 0..63
  u32 b0 = g*16u, hc0 = q*64u;
  for (u32 it=tid; it<256u; it+=512u){
    u32 gi = it>>6, col = gi*256u + hc0 + (it&63u);
    bsh[it] = bih[col] + bhh[col];
  }
  for (u32 it=tid; it<4096u; it+=512u){
    u32 r=it>>8, c=it&255u;
    Ahi[r*488u+224u+c]=0; Alo[r*488u+224u+c]=0;
    hfull[it]=0.0f;
  }
  {
    u32 r=tid>>5, t=tid&31u;
    const float* yr = y8 + ((u64)(b0+r)*32u + t)*224u;
    const float* we = attw + 256;
    float sacc=0.0f;
    #pragma unroll 8
    for (int j=0;j<224;j++) sacc += yr[j]*we[j];
    esc[r*33u+t] = sacc + attb[0];
  }
  float cst[2] = {0.0f, 0.0f};
  u32* fh = flags + g*16u;
  u32* fc = flags + g*16u + 8u;
  const u32 nt0 = w, nt1 = w + 8u;
  const u32 col0 = (nt0>>2)*256u + hc0 + (nt0&3u)*16u + nl;
  const u32 col1 = (nt1>>2)*256u + hc0 + (nt1&3u)*16u + nl;
  const u32 gl0  = (nt0>>2)*64u + (nt0&3u)*16u + nl;
  const u32 gl1  = (nt1>>2)*64u + (nt1&3u)*16u + nl;
  __syncthreads();
  for (u32 s=0; s<25u; s++){
    // ---- phase A: wait siblings' h[s-1], load packed h -> hfull + A-tile
    if (s>0u){
      if (tid==0u){
        while (__hip_atomic_load(fh, __ATOMIC_RELAXED, __HIP_MEMORY_SCOPE_AGENT) < 4u*s)
          __builtin_amdgcn_s_sleep(2);
      }
      __syncthreads();
      u32* hrow = hist + ((u64)(s-1u)*1024u + b0)*256u;
      for (u32 it=tid; it<4096u; it+=512u){
        u32 v = __hip_atomic_load(&hrow[it], __ATOMIC_RELAXED, __HIP_MEMORY_SCOPE_AGENT);
        u32 r = it>>8, c = it&255u;
        u16 hb = (u16)(v>>16), lb = (u16)(v&0xFFFFu);
        Ahi[r*488u+224u+c] = hb; Alo[r*488u+224u+c] = lb;
        hfull[it] = bf2f(hb) + bf2f(lb);
      }
      __syncthreads();
    }
    // ---- scores + softmax (redundant across the 4 siblings; cheap)
    {
      u32 r=tid>>5, t=tid&31u;
      float part=0.0f;
      if (s>0u){
        #pragma unroll
        for (int qq=0; qq<8; qq++){
          u32 c = t + (u32)qq*32u;
          part += hfull[r*256u+c]*attw[c];
        }
        #pragma unroll
        for (int off=16; off; off>>=1) part += __shfl_xor(part, off, 32);
      }
      float sv = esc[r*33u+t] + part;
      float mx = sv;
      #pragma unroll
      for (int off=16; off; off>>=1) mx = fmaxf(mx, __shfl_xor(mx, off, 32));
      float e = __expf(sv-mx);
      float ssum = e;
      #pragma unroll
      for (int off=16; off; off>>=1) ssum += __shfl_xor(ssum, off, 32);
      alp[r*33u+t] = e/ssum;
    }
    __syncthreads();
    // ---- phase B: ctx quarter (56 cols), pack hi|lo, write-through store
    u32* cdst = ctxc + (u64)(s&1u)*229376u + (u64)g*3584u;
    for (u32 it=tid; it<896u; it+=512u){
      u32 rr = it/56u, cc = it - rr*56u + q*56u;
      const float* yb = y8 + (u64)(b0+rr)*32u*224u + cc;
      float a0=0.0f;
      #pragma unroll
      for (int tt=0; tt<32; tt++) a0 += alp[rr*33u+(u32)tt]*yb[(u32)tt*224u];
      u16 hb = f2bf(a0), lb = f2bf(a0 - bf2f(hb));
      __hip_atomic_store(&cdst[rr*224u+cc], ((u32)hb<<16)|(u32)lb, __ATOMIC_RELAXED, __HIP_MEMORY_SCOPE_AGENT);
    }
    __syncthreads();  // drains vmcnt -> stores globally visible
    if (tid==0u){
      __hip_atomic_fetch_add(fc, 1u, __ATOMIC_RELEASE, __HIP_MEMORY_SCOPE_AGENT);
      while (__hip_atomic_load(fc, __ATOMIC_RELAXED, __HIP_MEMORY_SCOPE_AGENT) < 4u*(s+1u))
        __builtin_amdgcn_s_sleep(2);
    }
    __syncthreads();
    // ---- phase C: full ctx -> A-tile (L1-bypass loads; parity buffer)
    for (u32 it=tid; it<3584u; it+=512u){
      u32 v = __hip_atomic_load(&cdst[it], __ATOMIC_RELAXED, __HIP_MEMORY_SCOPE_AGENT);
      u32 rr = it/224u, cc = it - rr*224u;
      Ahi[rr*488u+cc] = (u16)(v>>16); Alo[rr*488u+cc] = (u16)(v&0xFFFFu);
    }
    __syncthreads();
    // ---- phase D: gates = [ctx|h] @ [Wih|Whh]^T for our 256 gate cols, 3-term split
    v4f acc0 = {}, acc1 = {};
    #pragma unroll
    for (int kt=0; kt<15; kt++){
      u32 ka = (u32)kt*32u + quad*8u;
      bfrag afh = *(const bfrag*)&Ahi[nl*488u + ka];
      bfrag afl = *(const bfrag*)&Alo[nl*488u + ka];
      bfrag b0h, b0l, b1h, b1l;
      if (kt<7){
        u64 o0 = (u64)col0*224u + ka, o1 = (u64)col1*224u + ka;
        b0h = *(const bfrag*)&WihHi[o0]; b0l = *(const bfrag*)&WihLo[o0];
        b1h = *(const bfrag*)&WihHi[o1]; b1l = *(const bfrag*)&WihLo[o1];
      } else {
        u32 kb = ka - 224u;
        u64 o0 = (u64)col0*256u + kb, o1 = (u64)col1*256u + kb;
        b0h = *(const bfrag*)&WhhHi[o0]; b0l = *(const bfrag*)&WhhLo[o0];
        b1h = *(const bfrag*)&WhhHi[o1]; b1l = *(const bfrag*)&WhhLo[o1];
      }
      acc0 = __builtin_amdgcn_mfma_f32_16x16x32_bf16(afh, b0h, acc0, 0,0,0);
      acc0 = __builtin_amdgcn_mfma_f32_16x16x32_bf16(afl, b0h, acc0, 0,0,0);
      acc0 = __builtin_amdgcn_mfma_f32_16x16x32_bf16(afh, b0l, acc0, 0,0,0);
      acc1 = __builtin_amdgcn_mfma_f32_16x16x32_bf16(afh, b1h, acc1, 0,0,0);
      acc1 = __builtin_amdgcn_mfma_f32_16x16x32_bf16(afl, b1h, acc1, 0,0,0);
      acc1 = __builtin_amdgcn_mfma_f32_16x16x32_bf16(afh, b1l, acc1, 0,0,0);
    }
    #pragma unroll
    for (int rg=0; rg<4; rg++){
      gsh[(quad*4u+(u32)rg)*260u + gl0] = acc0[rg];
      gsh[(quad*4u+(u32)rg)*260u + gl1] = acc1[rg];
    }
    __syncthreads();
    // ---- phase E: cell for our 64 h-cols; post packed h to hist[s]
    u32* hdst = hist + ((u64)s*1024u + b0)*256u + hc0;
    #pragma unroll
    for (int k2=0; k2<2; k2++){
      u32 l = (u32)k2*512u + tid;
      u32 row = l>>6, hl = l&63u;
      float gi_ = gsh[row*260u + hl]         + bsh[hl];
      float gf_ = gsh[row*260u + 64u  + hl]  + bsh[64u+hl];
      float gg_ = gsh[row*260u + 128u + hl]  + bsh[128u+hl];
      float go_ = gsh[row*260u + 192u + hl]  + bsh[192u+hl];
      float cv = sigm(gf_)*cst[k2] + sigm(gi_)*tanhf_(gg_);
      float hv = sigm(go_)*tanhf_(cv);
      cst[k2] = cv;
      u16 hb = f2bf(hv), lb = f2bf(hv - bf2f(hb));
      __hip_atomic_store(&hdst[row*256u + hl], ((u32)hb<<16)|(u32)lb, __ATOMIC_RELAXED, __HIP_MEMORY_SCOPE_AGENT);
    }
    __syncthreads();  // drains vmcnt
    if (tid==0u)
      __hip_atomic_fetch_add(fh, 1u, __ATOMIC_RELEASE, __HIP_MEMORY_SCOPE_AGENT);
  }
}

// ---------------- out projection from packed h history: (B, VOCAB, OUT_LEN) fp32
__global__ __launch_bounds__(256) void k_out(const u32* __restrict__ hist, const float* __restrict__ outw,
                                             const float* __restrict__ outb, float* __restrict__ outp){
  __shared__ __align__(16) float wsh[29*260];
  __shared__ __align__(16) float hrow[256];
  u32 tid = threadIdx.x, b = blockIdx.x;
  for (u32 it=tid; it<7424u; it+=256u){
    u32 v = it/256u, c = it&255u;
    wsh[v*260u+c] = outw[v*256u+c];
  }
  __syncthreads();
  for (u32 s=0; s<25u; s++){
    u32 v = hist[((u64)s*1024u + b)*256u + tid];
    hrow[tid] = bf2f((u16)(v>>16)) + bf2f((u16)(v&0xFFFFu));
    __syncthreads();
    if (tid < 232u){
      u32 vv = tid>>3, k8 = tid&7u;
      float a = 0.0f;
      #pragma unroll
      for (int j=0;j<32;j++) a += hrow[k8*32u+(u32)j]*wsh[vv*260u + k8*32u + (u32)j];
      #pragma unroll
      for (int off=4; off; off>>=1) a += __shfl_xor(a, off, 8);
      if (k8==0u) outp[((u64)b*29u + vv)*25u + s] = a + outb[vv];
    }
    __syncthreads();
  }
}

extern "C" void kernel_launch(void* const* d_in, const int* in_sizes, int n_in,
                              void* d_out, int out_size, void* d_ws, size_t ws_size,
                              hipStream_t stream){
  (void)in_sizes; (void)n_in; (void)out_size; (void)ws_size;
  const float* x    = (const float*)d_in[0];
  const float* c1w  = (const float*)d_in[1];
  const float* c1b  = (const float*)d_in[2];
  const float* c2w  = (const float*)d_in[3];
  const float* c2b  = (const float*)d_in[4];
  const float* c3w  = (const float*)d_in[5];
  const float* c3b  = (const float*)d_in[6];
  const float* c4w  = (const float*)d_in[7];
  const float* c4b  = (const float*)d_in[8];
  const float* h0   = (const float*)d_in[9];
  const float* c0   = (const float*)d_in[10];
  const float* lWih = (const float*)d_in[11];
  const float* lWhh = (const float*)d_in[12];
  const float* lbih = (const float*)d_in[13];
  const float* lbhh = (const float*)d_in[14];
  const float* attw = (const float*)d_in[15];
  const float* attb = (const float*)d_in[16];
  const float* dWih = (const float*)d_in[17];
  const float* dWhh = (const float*)d_in[18];
  const float* dbih = (const float*)d_in[19];
  const float* dbhh = (const float*)d_in[20];
  const float* outw = (const float*)d_in[21];
  const float* outb = (const float*)d_in[22];
  float* out = (float*)d_out;   // reference output dtype is float32
  char* ws = (char*)d_ws;
  // workspace (peak 62,291,968 B), with overlaps:
  //   y1q [0,22.02M) y2q [22.02,44.04M) y3 [44.04,58.72M)   (conv phase)
  //   y5  [0,29.36M)   (written by conv4 after y1q/y2q dead)
  //   y8  [29.36,58.72M) (written by k_enc7 after y2q/y3 dead)
  //   dec phase (y5 dead): hist [0,26.21M) ctxc [26.21,28.05M) flags [28.05M,+4K)
  //   enc flags live in d_out (fully overwritten by k_out afterwards)
  float* y1q = (float*)(ws);
  float* y2q = (float*)(ws + 22020096ull);
  float* y3  = (float*)(ws + 44040192ull);
  float* y5  = (float*)(ws);
  float* y8  = (float*)(ws + 29360128ull);
  u32* hist  = (u32*)(ws);
  u32* ctxc  = (u32*)(ws + 26214400ull);
  u32* flags = (u32*)(ws + 28049408ull);
  u16* lWihHi = (u16*)(ws + 58720256ull);
  u16* lWihLo = (u16*)(ws + 59121664ull);
  u16* lWhhHi = (u16*)(ws + 59523072ull);
  u16* lWhhLo = (u16*)(ws + 59924480ull);
  u16* dWihHi = (u16*)(ws + 60325888ull);
  u16* dWihLo = (u16*)(ws + 60784640ull);
  u16* dWhhHi = (u16*)(ws + 61243392ull);
  u16* dWhhLo = (u16*)(ws + 61767680ull);
  u32* eflags = (u32*)d_out;

  k_cvt4<<<dim3(3489), dim3(256), 0, stream>>>(lWih, lWihHi, lWihLo,
                                               lWhh, lWhhHi, lWhhLo,
                                               dWih, dWihHi, dWihLo,
                                               dWhh, dWhhHi, dWhhLo, eflags);
  for (u32 q=0; q<4; q++){
    k_conv1<<<dim3(768),  dim3(256), 0, stream>>>(x, c1w, c1b, y1q, q*256u);
    k_conv2<<<dim3(1536), dim3(256), 0, stream>>>(y1q, c2w, c2b, y2q);
    k_conv3<<<dim3(512),  dim3(256), 0, stream>>>(y2q, c3w, c3b, y3, q*256u);
  }
  k_conv4<<<dim3(2048), dim3(256), 0, stream>>>(y3, c4w, c4b, y5);
  k_enc7 <<<dim3(448), dim3(512), 0, stream>>>(lWihHi, lWihLo, lWhhHi, lWhhLo, lbih, lbhh,
                                               y5, h0, c0, y8, eflags);
  k_zero <<<dim3(1), dim3(1024), 0, stream>>>(flags);
  k_dec4 <<<dim3(256), dim3(512), 0, stream>>>(y8, attw, attb, dWihHi, dWihLo, dWhhHi, dWhhLo,
                                               dbih, dbhh, hist, ctxc, flags);
  k_out  <<<dim3(1024), dim3(256), 0, stream>>>(hist, outw, outb, out);
}